// Round 1
// baseline (292.395 us; speedup 1.0000x reference)
//
#include <hip/hip_runtime.h>

// GrCNet attention layer, restructured:
//   u[n] = W1 x[n], v[n] = W2 x[n]   (a = [W1 | W2], [64,128] row-major)
//   su[n] = u[n].a2, sv[n] = v[n].a2
//   per edge e: g = 0.5*(G[src,t]+G[dst,t]); raw = g*(su[src]+sv[dst])
//               ee = exp(-leakyrelu(raw)); w = ee*g
//               out[src] += w*(u[src]+v[dst]);  rowsum[src] += ee
//   out[n] = elu(out[n] / rowsum[n])

#define LRELU_ALPHA 0.2f

__global__ __launch_bounds__(256) void node_transform_kernel(
    const float* __restrict__ x, const float* __restrict__ a,
    const float* __restrict__ a2,
    float* __restrict__ u, float* __restrict__ v,
    float* __restrict__ su, float* __restrict__ sv, int N)
{
    // stage a [64][128] in LDS, padded to 129 so bank = (lane + i) % 32 (2-way, free)
    __shared__ float a_lds[64][129];
    for (int idx = threadIdx.x; idx < 64 * 128; idx += 256) {
        a_lds[idx >> 7][idx & 127] = a[idx];
    }
    __syncthreads();

    const int wave = threadIdx.x >> 6;
    const int lane = threadIdx.x & 63;
    const int n = blockIdx.x * 4 + wave;
    if (n >= N) return;

    const float a2v = a2[lane];
    const float* xr = x + (size_t)n * 64;
    float uo = 0.f, vo = 0.f;
#pragma unroll 8
    for (int i = 0; i < 64; ++i) {
        const float xi = xr[i];          // same addr across wave -> broadcast, L1-hit
        uo += xi * a_lds[lane][i];
        vo += xi * a_lds[lane][64 + i];
    }
    u[(size_t)n * 64 + lane] = uo;
    v[(size_t)n * 64 + lane] = vo;

    float sup = uo * a2v, svp = vo * a2v;
#pragma unroll
    for (int m = 1; m < 64; m <<= 1) {
        sup += __shfl_xor(sup, m, 64);
        svp += __shfl_xor(svp, m, 64);
    }
    if (lane == 0) { su[n] = sup; sv[n] = svp; }
}

__global__ __launch_bounds__(256) void edge_scatter_kernel(
    const int* __restrict__ edge, const int* __restrict__ etype,
    const float* __restrict__ G, int R,
    const float* __restrict__ u, const float* __restrict__ v,
    const float* __restrict__ su, const float* __restrict__ sv,
    float* __restrict__ out, float* __restrict__ rowsum,
    int E, int N)
{
    const int wave = threadIdx.x >> 6;
    const int lane = threadIdx.x & 63;
    const long long e = (long long)blockIdx.x * 4 + wave;
    if (e >= E) return;

    const int s = edge[e];
    const int d = edge[(size_t)E + e];
    const int t = etype[e];
    // defensive guard (also protects against a dtype-width surprise on the int inputs)
    if ((unsigned)s >= (unsigned)N || (unsigned)d >= (unsigned)N || (unsigned)t >= (unsigned)R)
        return;

    const float g   = 0.5f * (G[(size_t)s * R + t] + G[(size_t)d * R + t]);
    const float raw = g * (su[s] + sv[d]);
    const float lr  = raw > 0.f ? raw : LRELU_ALPHA * raw;
    const float ee  = __expf(-lr);
    const float w   = ee * g;

    const float val = w * (u[(size_t)s * 64 + lane] + v[(size_t)d * 64 + lane]);
    atomicAdd(&out[(size_t)s * 64 + lane], val);
    if (lane == 0) atomicAdd(&rowsum[s], ee);
}

__global__ __launch_bounds__(256) void finalize_kernel(
    float* __restrict__ out, const float* __restrict__ rowsum, int N)
{
    const int wave = threadIdx.x >> 6;
    const int lane = threadIdx.x & 63;
    const int n = blockIdx.x * 4 + wave;
    if (n >= N) return;

    float r = rowsum[n];
    r = (r == 0.f) ? 1e-12f : r;
    float h = out[(size_t)n * 64 + lane] / r;
    out[(size_t)n * 64 + lane] = (h > 0.f) ? h : expm1f(h);
}

extern "C" void kernel_launch(void* const* d_in, const int* in_sizes, int n_in,
                              void* d_out, int out_size, void* d_ws, size_t ws_size,
                              hipStream_t stream)
{
    const float* x     = (const float*)d_in[0];
    const int*   edge  = (const int*)d_in[1];
    // d_in[2] = edge_embed: unused by the reference computation
    const int*   etype = (const int*)d_in[3];
    const float* G     = (const float*)d_in[4];
    const float* a     = (const float*)d_in[5];
    const float* a2    = (const float*)d_in[6];

    const int N = in_sizes[0] / 64;
    const int E = in_sizes[1] / 2;
    const int R = in_sizes[4] / N;

    float* out = (float*)d_out;

    // workspace layout: u[N*64] | v[N*64] | su[N] | sv[N] | rowsum[N]  (~26.2 MB)
    float* u      = (float*)d_ws;
    float* v      = u + (size_t)N * 64;
    float* su     = v + (size_t)N * 64;
    float* sv     = su + N;
    float* rowsum = sv + N;

    hipMemsetAsync(out, 0, (size_t)N * 64 * sizeof(float), stream);
    hipMemsetAsync(rowsum, 0, (size_t)N * sizeof(float), stream);

    node_transform_kernel<<<dim3((N + 3) / 4), dim3(256), 0, stream>>>(
        x, a, a2, u, v, su, sv, N);
    edge_scatter_kernel<<<dim3((E + 3) / 4), dim3(256), 0, stream>>>(
        edge, etype, G, R, u, v, su, sv, out, rowsum, E, N);
    finalize_kernel<<<dim3((N + 3) / 4), dim3(256), 0, stream>>>(
        out, rowsum, N);
}

// Round 2
// 232.373 us; speedup vs baseline: 1.2583x; 1.2583x over previous
//
#include <hip/hip_runtime.h>

// GrCNet attention layer — CSR gather formulation (no vector atomics):
//   u[n] = W1 x[n], v[n] = W2 x[n]   (a = [W1 | W2], [64,128] row-major)
//   su[n] = u[n].a2, sv[n] = v[n].a2
//   edge e: g = 0.5*(G[s,t]+G[d,t]); ee = exp(-lrelu(g*(su[s]+sv[d]))); w = ee*g
//   CSR-by-src:  h[n] = elu( ((Σw)·u[n] + Σ w·v[d]) / Σee )

#define LRELU_ALPHA 0.2f
#define SCAN_BLOCK 256
#define SCAN_ITEMS 8
#define SCAN_TILE (SCAN_BLOCK * SCAN_ITEMS)  // 2048

__global__ __launch_bounds__(256) void node_transform_kernel(
    const float* __restrict__ x, const float* __restrict__ a,
    const float* __restrict__ a2,
    float* __restrict__ u, float* __restrict__ v,
    float* __restrict__ su, float* __restrict__ sv, int N)
{
    __shared__ float a_lds[64][129];
    for (int idx = threadIdx.x; idx < 64 * 128; idx += 256)
        a_lds[idx >> 7][idx & 127] = a[idx];
    __syncthreads();

    const int wave = threadIdx.x >> 6;
    const int lane = threadIdx.x & 63;
    const int n = blockIdx.x * 4 + wave;
    if (n >= N) return;

    const float a2v = a2[lane];
    const float* xr = x + (size_t)n * 64;
    float uo = 0.f, vo = 0.f;
#pragma unroll 8
    for (int i = 0; i < 64; ++i) {
        const float xi = xr[i];
        uo += xi * a_lds[lane][i];
        vo += xi * a_lds[lane][64 + i];
    }
    u[(size_t)n * 64 + lane] = uo;
    v[(size_t)n * 64 + lane] = vo;

    float sup = uo * a2v, svp = vo * a2v;
#pragma unroll
    for (int m = 1; m < 64; m <<= 1) {
        sup += __shfl_xor(sup, m, 64);
        svp += __shfl_xor(svp, m, 64);
    }
    if (lane == 0) { su[n] = sup; sv[n] = svp; }
}

__global__ __launch_bounds__(256) void hist_kernel(
    const int* __restrict__ edge, int* __restrict__ count, int E)
{
    const int i = blockIdx.x * 256 + threadIdx.x;
    if (i < E) atomicAdd(&count[edge[i]], 1);
}

__global__ __launch_bounds__(256) void scan_blocks_kernel(
    const int* __restrict__ count, int* __restrict__ base,
    int* __restrict__ blocksums, int N)
{
    __shared__ int lds[SCAN_BLOCK];
    const int b = blockIdx.x, t = threadIdx.x;
    const int idx0 = b * SCAN_TILE + t * SCAN_ITEMS;
    int vals[SCAN_ITEMS];
    int s = 0;
#pragma unroll
    for (int k = 0; k < SCAN_ITEMS; ++k) {
        const int idx = idx0 + k;
        const int c = (idx < N) ? count[idx] : 0;
        vals[k] = s; s += c;
    }
    lds[t] = s;
    __syncthreads();
    for (int off = 1; off < SCAN_BLOCK; off <<= 1) {
        const int x = (t >= off) ? lds[t - off] : 0;
        __syncthreads();
        lds[t] += x;
        __syncthreads();
    }
    const int excl = (t == 0) ? 0 : lds[t - 1];
#pragma unroll
    for (int k = 0; k < SCAN_ITEMS; ++k) {
        const int idx = idx0 + k;
        if (idx < N) base[idx] = excl + vals[k];
    }
    if (t == SCAN_BLOCK - 1) blocksums[b] = lds[t];
}

__global__ void scan_tops_kernel(int* __restrict__ blocksums, int nb)
{
    if (threadIdx.x == 0 && blockIdx.x == 0) {
        int s = 0;
        for (int i = 0; i < nb; ++i) { const int c = blocksums[i]; blocksums[i] = s; s += c; }
    }
}

__global__ __launch_bounds__(256) void scan_add_kernel(
    int* __restrict__ base, const int* __restrict__ blocksums,
    int* __restrict__ cursor, int N)
{
    const int i = blockIdx.x * 256 + threadIdx.x;
    if (i < N) {
        const int bv = base[i] + blocksums[i / SCAN_TILE];
        base[i] = bv;
        cursor[i] = bv;
    }
}

// one THREAD per edge: scalar score + CSR placement
__global__ __launch_bounds__(256) void edge_place_kernel(
    const int* __restrict__ edge, const int* __restrict__ etype,
    const float* __restrict__ G, int R,
    const float* __restrict__ su, const float* __restrict__ sv,
    int* __restrict__ cursor,
    int* __restrict__ csr_d, float* __restrict__ csr_w, float* __restrict__ csr_ee,
    int E, int N)
{
    const int e = blockIdx.x * 256 + threadIdx.x;
    if (e >= E) return;
    const int s = edge[e];
    const int d = edge[(size_t)E + e];
    const int t = etype[e];
    if ((unsigned)s >= (unsigned)N || (unsigned)d >= (unsigned)N) return;

    const float g   = 0.5f * (G[(size_t)s * R + t] + G[(size_t)d * R + t]);
    const float raw = g * (su[s] + sv[d]);
    const float lr  = raw > 0.f ? raw : LRELU_ALPHA * raw;
    const float ee  = __expf(-lr);

    const int pos = atomicAdd(&cursor[s], 1);
    csr_d[pos]  = d;
    csr_w[pos]  = ee * g;
    csr_ee[pos] = ee;
}

// one WAVE per node: register accumulation, fused finalize
__global__ __launch_bounds__(256) void aggregate_kernel(
    const int* __restrict__ base,
    const int* __restrict__ csr_d, const float* __restrict__ csr_w,
    const float* __restrict__ csr_ee,
    const float* __restrict__ u, const float* __restrict__ v,
    float* __restrict__ out, int N, int E)
{
    const int wave = threadIdx.x >> 6;
    const int lane = threadIdx.x & 63;
    const int n = blockIdx.x * 4 + wave;
    if (n >= N) return;

    const int rs = base[n];
    const int re = (n + 1 < N) ? base[n + 1] : E;

    float val = 0.f, sumw_p = 0.f, sumee_p = 0.f;

    for (int i = rs; i < re; i += 64) {
        const int m = min(64, re - i);
        int dl = 0; float wl = 0.f, eel = 0.f;
        if (lane < m) {
            dl  = csr_d[i + lane];
            wl  = csr_w[i + lane];
            eel = csr_ee[i + lane];
        }
        sumw_p  += wl;
        sumee_p += eel;
        for (int j = 0; j < m; ++j) {
            const int   dj = __shfl(dl, j, 64);
            const float wj = __shfl(wl, j, 64);
            val += wj * v[(size_t)dj * 64 + lane];
        }
    }

    float sumw = sumw_p, sumee = sumee_p;
#pragma unroll
    for (int m2 = 1; m2 < 64; m2 <<= 1) {
        sumw  += __shfl_xor(sumw,  m2, 64);
        sumee += __shfl_xor(sumee, m2, 64);
    }

    val += sumw * u[(size_t)n * 64 + lane];
    const float r = (sumee == 0.f) ? 1e-12f : sumee;
    const float h = val / r;
    out[(size_t)n * 64 + lane] = (h > 0.f) ? h : expm1f(h);
}

extern "C" void kernel_launch(void* const* d_in, const int* in_sizes, int n_in,
                              void* d_out, int out_size, void* d_ws, size_t ws_size,
                              hipStream_t stream)
{
    const float* x     = (const float*)d_in[0];
    const int*   edge  = (const int*)d_in[1];
    // d_in[2] = edge_embed: unused by the reference computation
    const int*   etype = (const int*)d_in[3];
    const float* G     = (const float*)d_in[4];
    const float* a     = (const float*)d_in[5];
    const float* a2    = (const float*)d_in[6];

    const int N = in_sizes[0] / 64;
    const int E = in_sizes[1] / 2;
    const int R = in_sizes[4] / N;

    float* out = (float*)d_out;

    // workspace layout (~36.3 MB):
    // u[N*64] | v[N*64] | su[N] | sv[N] | count[N] | base[N] | cursor[N] |
    // blocksums[nsb] | csr_d[E] | csr_w[E] | csr_ee[E]
    float* u      = (float*)d_ws;
    float* v      = u + (size_t)N * 64;
    float* su     = v + (size_t)N * 64;
    float* sv     = su + N;
    int*   count  = (int*)(sv + N);
    int*   base   = count + N;
    int*   cursor = base + N;
    const int nsb = (N + SCAN_TILE - 1) / SCAN_TILE;
    int*   blocksums = cursor + N;
    int*   csr_d  = blocksums + ((nsb + 63) & ~63);
    float* csr_w  = (float*)(csr_d + E);
    float* csr_ee = csr_w + E;

    hipMemsetAsync(count, 0, (size_t)N * sizeof(int), stream);

    node_transform_kernel<<<dim3((N + 3) / 4), dim3(256), 0, stream>>>(
        x, a, a2, u, v, su, sv, N);
    hist_kernel<<<dim3((E + 255) / 256), dim3(256), 0, stream>>>(edge, count, E);
    scan_blocks_kernel<<<dim3(nsb), dim3(SCAN_BLOCK), 0, stream>>>(count, base, blocksums, N);
    scan_tops_kernel<<<dim3(1), dim3(64), 0, stream>>>(blocksums, nsb);
    scan_add_kernel<<<dim3((N + 255) / 256), dim3(256), 0, stream>>>(base, blocksums, cursor, N);
    edge_place_kernel<<<dim3((E + 255) / 256), dim3(256), 0, stream>>>(
        edge, etype, G, R, su, sv, cursor, csr_d, csr_w, csr_ee, E, N);
    aggregate_kernel<<<dim3((N + 3) / 4), dim3(256), 0, stream>>>(
        base, csr_d, csr_w, csr_ee, u, v, out, N, E);
}

// Round 3
// 227.456 us; speedup vs baseline: 1.2855x; 1.0216x over previous
//
#include <hip/hip_runtime.h>

// GrCNet attention layer — CSR gather formulation (no vector atomics):
//   u[n] = W1 x[n], v[n] = W2 x[n]   (a = [W1 | W2], [64,128] row-major)
//   su[n] = u[n].a2, sv[n] = v[n].a2
//   edge e: g = 0.5*(G[s,t]+G[d,t]); ee = exp(-lrelu(g*(su[s]+sv[d]))); w = ee*g
//   CSR-by-src:  h[n] = elu( ((Σw)·u[n] + Σ w·v[d]) / Σee )
//
// Round 3: hipMemsetAsync(count) was a 119 µs rocclr fillBuffer dispatch
// (half the total!) — count[] is now zeroed inside node_transform_kernel.

#define LRELU_ALPHA 0.2f
#define SCAN_BLOCK 256
#define SCAN_ITEMS 8
#define SCAN_TILE (SCAN_BLOCK * SCAN_ITEMS)  // 2048

__global__ __launch_bounds__(256) void node_transform_kernel(
    const float* __restrict__ x, const float* __restrict__ a,
    const float* __restrict__ a2,
    float* __restrict__ u, float* __restrict__ v,
    float* __restrict__ su, float* __restrict__ sv,
    int* __restrict__ count, int N)
{
    __shared__ float a_lds[64][129];
    for (int idx = threadIdx.x; idx < 64 * 128; idx += 256)
        a_lds[idx >> 7][idx & 127] = a[idx];
    __syncthreads();

    const int wave = threadIdx.x >> 6;
    const int lane = threadIdx.x & 63;
    const int n = blockIdx.x * 4 + wave;
    if (n >= N) return;

    if (lane == 0) count[n] = 0;   // replaces the 119 us rocclr fill

    const float a2v = a2[lane];
    const float* xr = x + (size_t)n * 64;
    float uo = 0.f, vo = 0.f;
#pragma unroll 8
    for (int i = 0; i < 64; ++i) {
        const float xi = xr[i];
        uo += xi * a_lds[lane][i];
        vo += xi * a_lds[lane][64 + i];
    }
    u[(size_t)n * 64 + lane] = uo;
    v[(size_t)n * 64 + lane] = vo;

    float sup = uo * a2v, svp = vo * a2v;
#pragma unroll
    for (int m = 1; m < 64; m <<= 1) {
        sup += __shfl_xor(sup, m, 64);
        svp += __shfl_xor(svp, m, 64);
    }
    if (lane == 0) { su[n] = sup; sv[n] = svp; }
}

__global__ __launch_bounds__(256) void hist_kernel(
    const int* __restrict__ edge, int* __restrict__ count, int E)
{
    const int i = blockIdx.x * 256 + threadIdx.x;
    if (i < E) atomicAdd(&count[edge[i]], 1);
}

__global__ __launch_bounds__(256) void scan_blocks_kernel(
    const int* __restrict__ count, int* __restrict__ base,
    int* __restrict__ blocksums, int N)
{
    __shared__ int lds[SCAN_BLOCK];
    const int b = blockIdx.x, t = threadIdx.x;
    const int idx0 = b * SCAN_TILE + t * SCAN_ITEMS;
    int vals[SCAN_ITEMS];
    int s = 0;
#pragma unroll
    for (int k = 0; k < SCAN_ITEMS; ++k) {
        const int idx = idx0 + k;
        const int c = (idx < N) ? count[idx] : 0;
        vals[k] = s; s += c;
    }
    lds[t] = s;
    __syncthreads();
    for (int off = 1; off < SCAN_BLOCK; off <<= 1) {
        const int x = (t >= off) ? lds[t - off] : 0;
        __syncthreads();
        lds[t] += x;
        __syncthreads();
    }
    const int excl = (t == 0) ? 0 : lds[t - 1];
#pragma unroll
    for (int k = 0; k < SCAN_ITEMS; ++k) {
        const int idx = idx0 + k;
        if (idx < N) base[idx] = excl + vals[k];
    }
    if (t == SCAN_BLOCK - 1) blocksums[b] = lds[t];
}

__global__ void scan_tops_kernel(int* __restrict__ blocksums, int nb)
{
    if (threadIdx.x == 0 && blockIdx.x == 0) {
        int s = 0;
        for (int i = 0; i < nb; ++i) { const int c = blocksums[i]; blocksums[i] = s; s += c; }
    }
}

__global__ __launch_bounds__(256) void scan_add_kernel(
    int* __restrict__ base, const int* __restrict__ blocksums,
    int* __restrict__ cursor, int N)
{
    const int i = blockIdx.x * 256 + threadIdx.x;
    if (i < N) {
        const int bv = base[i] + blocksums[i / SCAN_TILE];
        base[i] = bv;
        cursor[i] = bv;
    }
}

// one THREAD per edge: scalar score + CSR placement
__global__ __launch_bounds__(256) void edge_place_kernel(
    const int* __restrict__ edge, const int* __restrict__ etype,
    const float* __restrict__ G, int R,
    const float* __restrict__ su, const float* __restrict__ sv,
    int* __restrict__ cursor,
    int* __restrict__ csr_d, float* __restrict__ csr_w, float* __restrict__ csr_ee,
    int E, int N)
{
    const int e = blockIdx.x * 256 + threadIdx.x;
    if (e >= E) return;
    const int s = edge[e];
    const int d = edge[(size_t)E + e];
    const int t = etype[e];
    if ((unsigned)s >= (unsigned)N || (unsigned)d >= (unsigned)N) return;

    const float g   = 0.5f * (G[(size_t)s * R + t] + G[(size_t)d * R + t]);
    const float raw = g * (su[s] + sv[d]);
    const float lr  = raw > 0.f ? raw : LRELU_ALPHA * raw;
    const float ee  = __expf(-lr);

    const int pos = atomicAdd(&cursor[s], 1);
    csr_d[pos]  = d;
    csr_w[pos]  = ee * g;
    csr_ee[pos] = ee;
}

// one WAVE per node: register accumulation, fused finalize
__global__ __launch_bounds__(256) void aggregate_kernel(
    const int* __restrict__ base,
    const int* __restrict__ csr_d, const float* __restrict__ csr_w,
    const float* __restrict__ csr_ee,
    const float* __restrict__ u, const float* __restrict__ v,
    float* __restrict__ out, int N, int E)
{
    const int wave = threadIdx.x >> 6;
    const int lane = threadIdx.x & 63;
    const int n = blockIdx.x * 4 + wave;
    if (n >= N) return;

    const int rs = base[n];
    const int re = (n + 1 < N) ? base[n + 1] : E;

    float val = 0.f, sumw_p = 0.f, sumee_p = 0.f;

    for (int i = rs; i < re; i += 64) {
        const int m = min(64, re - i);
        int dl = 0; float wl = 0.f, eel = 0.f;
        if (lane < m) {
            dl  = csr_d[i + lane];
            wl  = csr_w[i + lane];
            eel = csr_ee[i + lane];
        }
        sumw_p  += wl;
        sumee_p += eel;
        for (int j = 0; j < m; ++j) {
            const int   dj = __shfl(dl, j, 64);
            const float wj = __shfl(wl, j, 64);
            val += wj * v[(size_t)dj * 64 + lane];
        }
    }

    float sumw = sumw_p, sumee = sumee_p;
#pragma unroll
    for (int m2 = 1; m2 < 64; m2 <<= 1) {
        sumw  += __shfl_xor(sumw,  m2, 64);
        sumee += __shfl_xor(sumee, m2, 64);
    }

    val += sumw * u[(size_t)n * 64 + lane];
    const float r = (sumee == 0.f) ? 1e-12f : sumee;
    const float h = val / r;
    out[(size_t)n * 64 + lane] = (h > 0.f) ? h : expm1f(h);
}

extern "C" void kernel_launch(void* const* d_in, const int* in_sizes, int n_in,
                              void* d_out, int out_size, void* d_ws, size_t ws_size,
                              hipStream_t stream)
{
    const float* x     = (const float*)d_in[0];
    const int*   edge  = (const int*)d_in[1];
    // d_in[2] = edge_embed: unused by the reference computation
    const int*   etype = (const int*)d_in[3];
    const float* G     = (const float*)d_in[4];
    const float* a     = (const float*)d_in[5];
    const float* a2    = (const float*)d_in[6];

    const int N = in_sizes[0] / 64;
    const int E = in_sizes[1] / 2;
    const int R = in_sizes[4] / N;

    float* out = (float*)d_out;

    // workspace layout (~36.3 MB):
    // u[N*64] | v[N*64] | su[N] | sv[N] | count[N] | base[N] | cursor[N] |
    // blocksums[nsb] | csr_d[E] | csr_w[E] | csr_ee[E]
    float* u      = (float*)d_ws;
    float* v      = u + (size_t)N * 64;
    float* su     = v + (size_t)N * 64;
    float* sv     = su + N;
    int*   count  = (int*)(sv + N);
    int*   base   = count + N;
    int*   cursor = base + N;
    const int nsb = (N + SCAN_TILE - 1) / SCAN_TILE;
    int*   blocksums = cursor + N;
    int*   csr_d  = blocksums + ((nsb + 63) & ~63);
    float* csr_w  = (float*)(csr_d + E);
    float* csr_ee = csr_w + E;

    node_transform_kernel<<<dim3((N + 3) / 4), dim3(256), 0, stream>>>(
        x, a, a2, u, v, su, sv, count, N);
    hist_kernel<<<dim3((E + 255) / 256), dim3(256), 0, stream>>>(edge, count, E);
    scan_blocks_kernel<<<dim3(nsb), dim3(SCAN_BLOCK), 0, stream>>>(count, base, blocksums, N);
    scan_tops_kernel<<<dim3(1), dim3(64), 0, stream>>>(blocksums, nsb);
    scan_add_kernel<<<dim3((N + 255) / 256), dim3(256), 0, stream>>>(base, blocksums, cursor, N);
    edge_place_kernel<<<dim3((E + 255) / 256), dim3(256), 0, stream>>>(
        edge, etype, G, R, su, sv, cursor, csr_d, csr_w, csr_ee, E, N);
    aggregate_kernel<<<dim3((N + 3) / 4), dim3(256), 0, stream>>>(
        base, csr_d, csr_w, csr_ee, u, v, out, N, E);
}